// Round 15
// baseline (192.313 us; speedup 1.0000x reference)
//
#include <hip/hip_runtime.h>
#include <hip/hip_bf16.h>

#define NN 50000
#define EE 800000
#define DD 128
#define HH 128
#define CC 16
#define GG 512
#define NBLK_N 196       // ceil(50000/256)
#define NPAD 50176       // padded rows for bf16 feature buffers
#define GEMM_BLOCKS 782  // ceil(50000/64)
#define FILL_BLOCKS 3125
#define DEG_BLOCKS 3125
#define INIT_BLOCKS 64
#define CAP 64           // fixed adj slots per node (max deg ~40 for Poisson(16))
#define POOLF (4 * GG * HH + GG)   // pool floats (gsum0,gmax0,gsum1,gmax1,cnt)

typedef __attribute__((ext_vector_type(8))) short short8v;
typedef __attribute__((ext_vector_type(8))) unsigned short ushort8v;
typedef __attribute__((ext_vector_type(4))) float f32x4;

__device__ inline unsigned short f2bf(float x) {  // RNE
    unsigned int u = __float_as_uint(x);
    u += 0x7fffu + ((u >> 16) & 1u);
    return (unsigned short)(u >> 16);
}

// ---------------- zero deg + cursor (must precede deg atomics / fill) ----------------
__global__ __launch_bounds__(256) void k_zero(int* __restrict__ deg, int* __restrict__ cursor) {
    int i = blockIdx.x * 256 + threadIdx.x;
    if (i < NPAD) { deg[i] = 0; cursor[i] = 0; }
}

// ---------------- deg atomics (blocks 0..3124) + pools-zero/W-pack (extra blocks) ----------------
__global__ __launch_bounds__(256) void k_deginit(const int* __restrict__ ei, int* __restrict__ deg,
                                                 float* __restrict__ pools,
                                                 const float* __restrict__ W1, const float* __restrict__ W2,
                                                 unsigned short* __restrict__ Wf) {
    if (blockIdx.x < DEG_BLOCKS) {
        int e = blockIdx.x * 256 + threadIdx.x;
        if (e < EE) atomicAdd(&deg[ei[EE + e]], 1);
    } else {
        int t2 = (blockIdx.x - DEG_BLOCKS) * 256 + threadIdx.x;
        const int nt2 = INIT_BLOCKS * 256;
        for (int i = t2; i < POOLF; i += nt2) pools[i] = 0.0f;
        for (int idx = t2; idx < 4096; idx += nt2) {
            const float* W = (idx >> 11) ? W2 : W1;
            int id2 = idx & 2047;
            int lane = id2 & 63, ct = (id2 >> 6) & 7, kt = id2 >> 9;
            int col = ct * 16 + (lane & 15);
            int k0 = kt * 32 + (lane >> 4) * 8;
            ushort8v v;
            #pragma unroll
            for (int j = 0; j < 8; ++j) v[j] = f2bf(W[(k0 + j) * 128 + col]);
            *(ushort8v*)(Wf + idx * 8) = v;
        }
    }
}

// ---------------- dis = rsqrt(deg+1) ----------------
__global__ __launch_bounds__(256) void k_dis(const int* __restrict__ deg, float* __restrict__ dis) {
    int i = blockIdx.x * 256 + threadIdx.x;
    if (i < NN) dis[i] = rsqrtf((float)deg[i] + 1.0f);  // +1 self loop
}

// ---------------- fused launch: gemm1 (blocks 0..781, LDS W, dis folded into A) + CSR fill ----------------
// gemm: O[row] = bf16( (Af[row]*dis[row]) @ W1 )
// fill (fixed slots): adj[(d<<6)+pos] = (src<<16) | bf16(dis[s]*dis[d])
//   -- dis gathers stagger thread arrival at the cursor atomic + scattered store (r12-verified);
//   -- plain stores: L2 write-combines the scattered 4B adj writes (NT store was -20%, r13)
__global__ __launch_bounds__(256) void k_fillgemm(const float* __restrict__ Af,
                                                  const unsigned short* __restrict__ Wf,
                                                  const float* __restrict__ dis,
                                                  unsigned short* __restrict__ O,
                                                  const int* __restrict__ ei,
                                                  int* __restrict__ cursor,
                                                  unsigned int* __restrict__ adj) {
    __shared__ unsigned short Wl[16384];  // 32 KB (gemm branch only)
    if (blockIdx.x < GEMM_BLOCKS) {
        #pragma unroll
        for (int idx = threadIdx.x; idx < 2048; idx += 256)
            *(ushort8v*)(Wl + idx * 8) = *(const ushort8v*)(Wf + idx * 8);
        __syncthreads();

        int wid = threadIdx.x >> 6, lane = threadIdx.x & 63;
        int b = lane >> 4;
        int row = blockIdx.x * 64 + wid * 16 + (lane & 15);
        int r = min(row, NN - 1);
        float dr = dis[r];                    // A row scale (norm factored: h' = (x*dis)@W)
        const float* ap = Af + (size_t)r * 128 + b * 8;
        short8v a[4];
        #pragma unroll
        for (int kt = 0; kt < 4; ++kt) {
            float4 f0 = *(const float4*)(ap + kt * 32);
            float4 f1 = *(const float4*)(ap + kt * 32 + 4);
            short8v v;
            v[0] = (short)f2bf(f0.x * dr); v[1] = (short)f2bf(f0.y * dr);
            v[2] = (short)f2bf(f0.z * dr); v[3] = (short)f2bf(f0.w * dr);
            v[4] = (short)f2bf(f1.x * dr); v[5] = (short)f2bf(f1.y * dr);
            v[6] = (short)f2bf(f1.z * dr); v[7] = (short)f2bf(f1.w * dr);
            a[kt] = v;
        }
        f32x4 z = 0.0f;
        f32x4 acc[8] = {z, z, z, z, z, z, z, z};
        #pragma unroll
        for (int kt = 0; kt < 4; ++kt) {
            #pragma unroll
            for (int ct = 0; ct < 8; ++ct) {
                short8v bfrag = *(const short8v*)(Wl + ((kt * 8 + ct) * 64 + lane) * 8);
                acc[ct] = __builtin_amdgcn_mfma_f32_16x16x32_bf16(a[kt], bfrag, acc[ct], 0, 0, 0);
            }
        }
        // C/D: row = (lane>>4)*4 + j, col = ct*16 + (lane&15)   [m89-verified]
        int orow = blockIdx.x * 64 + wid * 16 + b * 4;
        unsigned short* op = O + (size_t)orow * 128 + (lane & 15);
        #pragma unroll
        for (int j = 0; j < 4; ++j) {
            #pragma unroll
            for (int ct = 0; ct < 8; ++ct)
                op[(size_t)j * 128 + ct * 16] = f2bf(acc[ct][j]);
        }
    } else {
        int e = (blockIdx.x - GEMM_BLOCKS) * 256 + threadIdx.x;
        if (e < EE) {
            int s = ei[e];
            int d = ei[EE + e];
            float nrm = dis[s] * dis[d];
            int pos = atomicAdd(&cursor[d], 1);
            adj[((unsigned int)d << 6) + pos] = ((unsigned int)s << 16) | (unsigned int)f2bf(nrm);
        }
    }
}

// ---------------- fused gather conv + self + bias + relu + pool (+ optional fused GEMM2) ----------------
// h holds h' = (x*dis)@W ; conv computes relu(dis[d] * (sum_{s in N(d)} h'[s] + h'[d]) + bias)
// adj stripe for node = adj[node*64 .. node*64+deg) ; entry = (src<<16)|norm16, only src used.
// 2-deep adj prefetch: window w+1's adj word loads while w's gathers are in flight.
// flags: 2 = count nodes per graph, 4 = fused gemm2 epilogue ((lacc*dis) @ W2f -> h2out)
__global__ __launch_bounds__(256) void k_conv(const unsigned short* __restrict__ h,
                                              const unsigned int* __restrict__ adj,
                                              const int* __restrict__ deg,
                                              const float* __restrict__ dis,
                                              const float* __restrict__ bias,
                                              const int* __restrict__ batch,
                                              const unsigned short* __restrict__ W2f,
                                              unsigned short* __restrict__ h2out,
                                              float* __restrict__ gsum,
                                              float* __restrict__ gmax,
                                              float* __restrict__ cnt,
                                              int flags) {
    __shared__ float lacc[16][132];   // stride 132 -> 16B-aligned rows, 2-way bank alias only
    __shared__ int lb[16];
    __shared__ float sdis[16];
    const int tid = threadIdx.x;
    const int wid = tid >> 6, lane = tid & 63;
    const int g = lane >> 4, l = lane & 15;
    const int nrow = wid * 4 + g;
    const int node = blockIdx.x * 16 + nrow;
    const int fb = l * 8;   // 8 features per lane

    const float di = dis[node];
    const uint4 hv = *(const uint4*)(h + (size_t)node * 128 + fb);
    const float4 bv0 = *(const float4*)(bias + fb);
    const float4 bv1 = *(const float4*)(bias + fb + 4);
    float acc[8];
    acc[0] = __uint_as_float(hv.x << 16);
    acc[1] = __uint_as_float(hv.x & 0xffff0000u);
    acc[2] = __uint_as_float(hv.y << 16);
    acc[3] = __uint_as_float(hv.y & 0xffff0000u);
    acc[4] = __uint_as_float(hv.z << 16);
    acc[5] = __uint_as_float(hv.z & 0xffff0000u);
    acc[6] = __uint_as_float(hv.w << 16);
    acc[7] = __uint_as_float(hv.w & 0xffff0000u);

    const int n = deg[node];            // uniform within 16-lane group
    const unsigned int* ap = adj + ((size_t)node << 6);
    const int sl = lane & 48;           // group base lane (g*16)

    if (n > 0) {
        unsigned int e = ap[min(l, n - 1)];
        for (int k = 0; k < n; k += 16) {
            unsigned int ecur = e;
            int kn = k + 16;
            if (kn < n) e = ap[min(kn + l, n - 1)];   // prefetch next window
            if (kn <= n) {                             // full window, unmasked
                #pragma unroll
                for (int j = 0; j < 16; ++j) {
                    unsigned int ej = __shfl(ecur, sl + j) >> 16;
                    const uint4 v = *(const uint4*)(h + (size_t)ej * 128 + fb);
                    acc[0] += __uint_as_float(v.x << 16);
                    acc[1] += __uint_as_float(v.x & 0xffff0000u);
                    acc[2] += __uint_as_float(v.y << 16);
                    acc[3] += __uint_as_float(v.y & 0xffff0000u);
                    acc[4] += __uint_as_float(v.z << 16);
                    acc[5] += __uint_as_float(v.z & 0xffff0000u);
                    acc[6] += __uint_as_float(v.w << 16);
                    acc[7] += __uint_as_float(v.w & 0xffff0000u);
                }
            } else {                                   // masked tail window
                #pragma unroll
                for (int j = 0; j < 16; ++j) {
                    unsigned int ej = __shfl(ecur, sl + j) >> 16;
                    float w = (k + j < n) ? 1.0f : 0.0f;
                    const uint4 v = *(const uint4*)(h + (size_t)ej * 128 + fb);
                    acc[0] = fmaf(__uint_as_float(v.x << 16),         w, acc[0]);
                    acc[1] = fmaf(__uint_as_float(v.x & 0xffff0000u), w, acc[1]);
                    acc[2] = fmaf(__uint_as_float(v.y << 16),         w, acc[2]);
                    acc[3] = fmaf(__uint_as_float(v.y & 0xffff0000u), w, acc[3]);
                    acc[4] = fmaf(__uint_as_float(v.z << 16),         w, acc[4]);
                    acc[5] = fmaf(__uint_as_float(v.z & 0xffff0000u), w, acc[5]);
                    acc[6] = fmaf(__uint_as_float(v.w << 16),         w, acc[6]);
                    acc[7] = fmaf(__uint_as_float(v.w & 0xffff0000u), w, acc[7]);
                }
            }
        }
    }
    float bvv[8] = {bv0.x, bv0.y, bv0.z, bv0.w, bv1.x, bv1.y, bv1.z, bv1.w};
    #pragma unroll
    for (int p = 0; p < 8; ++p) {
        float v = fmaxf(fmaf(di, acc[p], bvv[p]), 0.0f);
        lacc[nrow][fb + p] = v;
    }
    if (l == 0) lb[nrow] = batch[node];
    if (tid < 16) sdis[tid] = dis[blockIdx.x * 16 + tid];
    __syncthreads();

    // ---- block pool pre-reduction over 16 sorted nodes ----
    {
        const int f = tid & 127;
        const bool domax = tid >= 128;
        float s = lacc[0][f];
        int cur = lb[0], run = 1;
        #pragma unroll
        for (int w = 1; w < 16; ++w) {
            float a = lacc[w][f];
            if (lb[w] == cur) {
                s = domax ? fmaxf(s, a) : (s + a);
                ++run;
            } else {
                if (domax) {
                    atomicMax((int*)&gmax[cur * 128 + f], __float_as_int(s));
                } else {
                    atomicAdd(&gsum[cur * 128 + f], s);
                    if (f == 0 && (flags & 2)) atomicAdd(cnt + cur, (float)run);
                }
                s = a; cur = lb[w]; run = 1;
            }
        }
        if (domax) {
            atomicMax((int*)&gmax[cur * 128 + f], __float_as_int(s));
        } else {
            atomicAdd(&gsum[cur * 128 + f], s);
            if (f == 0 && (flags & 2)) atomicAdd(cnt + cur, (float)run);
        }
    }

    // ---- fused GEMM2: h2' = (lacc*dis) @ W2, written to h2out (dis folded into A rows) ----
    if (flags & 4) {
        const int ct0 = wid * 2, ct1 = wid * 2 + 1;
        const float dr = sdis[lane & 15];   // A row = lane&15
        f32x4 c0 = 0.0f, c1 = 0.0f;
        #pragma unroll
        for (int kt = 0; kt < 4; ++kt) {
            const float* arow = &lacc[lane & 15][kt * 32 + (lane >> 4) * 8];
            float4 fa = *(const float4*)arow;
            float4 fc = *(const float4*)(arow + 4);
            short8v af;
            af[0] = (short)f2bf(fa.x * dr); af[1] = (short)f2bf(fa.y * dr);
            af[2] = (short)f2bf(fa.z * dr); af[3] = (short)f2bf(fa.w * dr);
            af[4] = (short)f2bf(fc.x * dr); af[5] = (short)f2bf(fc.y * dr);
            af[6] = (short)f2bf(fc.z * dr); af[7] = (short)f2bf(fc.w * dr);
            short8v b0 = *(const short8v*)(W2f + ((kt * 8 + ct0) * 64 + lane) * 8);
            short8v b1 = *(const short8v*)(W2f + ((kt * 8 + ct1) * 64 + lane) * 8);
            c0 = __builtin_amdgcn_mfma_f32_16x16x32_bf16(af, b0, c0, 0, 0, 0);
            c1 = __builtin_amdgcn_mfma_f32_16x16x32_bf16(af, b1, c1, 0, 0, 0);
        }
        const int node0 = blockIdx.x * 16;
        #pragma unroll
        for (int j = 0; j < 4; ++j) {
            int r = (lane >> 4) * 4 + j;
            unsigned short* op = h2out + (size_t)(node0 + r) * 128 + (lane & 15);
            op[ct0 * 16] = f2bf(c0[j]);
            op[ct1 * 16] = f2bf(c1[j]);
        }
    }
}

// ---------------- final MLP: one block per graph ----------------
__global__ __launch_bounds__(256) void k_mlp(const float* __restrict__ gsum0,
                                             const float* __restrict__ gmax0,
                                             const float* __restrict__ gsum1,
                                             const float* __restrict__ gmax1,
                                             const float* __restrict__ cnt,
                                             const float* __restrict__ lW1,
                                             const float* __restrict__ lb1,
                                             const float* __restrict__ lW2,
                                             const float* __restrict__ lb2,
                                             float* __restrict__ out) {
    __shared__ float gl[512];
    __shared__ float hb[256];
    __shared__ float part[256];
    int r = blockIdx.x;
    float inv = 1.0f / fmaxf(cnt[r], 1.0f);
    for (int k = threadIdx.x; k < 512; k += 256) {
        int seg = k >> 7, f = k & 127;
        float v;
        if (seg == 0)      v = gsum0[r * 128 + f] * inv;
        else if (seg == 1) v = gmax0[r * 128 + f];
        else if (seg == 2) v = gsum1[r * 128 + f] * inv;
        else               v = gmax1[r * 128 + f];
        gl[k] = v;
    }
    __syncthreads();
    {
        int j = threadIdx.x;
        float acc = lb1[j];
        for (int k = 0; k < 512; ++k) acc += gl[k] * lW1[k * 256 + j];
        hb[j] = fmaxf(acc, 0.f);
    }
    __syncthreads();
    {
        int c = threadIdx.x & 15, ch = threadIdx.x >> 4;
        float p = 0.f;
        #pragma unroll
        for (int j2 = 0; j2 < 16; ++j2) p += hb[ch * 16 + j2] * lW2[(ch * 16 + j2) * 16 + c];
        part[threadIdx.x] = p;
    }
    __syncthreads();
    if (threadIdx.x < 16) {
        float s = lb2[threadIdx.x];
        #pragma unroll
        for (int ch2 = 0; ch2 < 16; ++ch2) s += part[ch2 * 16 + threadIdx.x];
        out[r * 16 + threadIdx.x] = s;
    }
}

extern "C" void kernel_launch(void* const* d_in, const int* in_sizes, int n_in,
                              void* d_out, int out_size, void* d_ws, size_t ws_size,
                              hipStream_t stream) {
    const float* x    = (const float*)d_in[0];
    const int*   ei   = (const int*)d_in[1];
    const int*   batch= (const int*)d_in[2];
    const float* W1   = (const float*)d_in[3];
    const float* b1   = (const float*)d_in[4];
    const float* W2   = (const float*)d_in[5];
    const float* b2   = (const float*)d_in[6];
    const float* lW1  = (const float*)d_in[7];
    const float* lb1  = (const float*)d_in[8];
    const float* lW2  = (const float*)d_in[9];
    const float* lb2  = (const float*)d_in[10];
    float* out = (float*)d_out;

    // ---- workspace layout ----
    unsigned short* hbuf = (unsigned short*)d_ws;          // NPAD*128 bf16 (h1')
    unsigned short* h2b  = hbuf + (size_t)NPAD * 128;      // NPAD*128 bf16 (h2')
    unsigned short* wf   = h2b + (size_t)NPAD * 128;       // 2*16384 bf16 frag-packed W1,W2
    float* dis   = (float*)(wf + 32768);                   // NPAD f32
    float* gsum0 = dis + NPAD;
    float* gmax0 = gsum0 + GG * HH;
    float* gsum1 = gmax0 + GG * HH;
    float* gmax1 = gsum1 + GG * HH;
    float* cnt   = gmax1 + GG * HH;                        // G
    int*   deg    = (int*)(cnt + GG);                      // NPAD
    int*   cursor = deg + NPAD;                            // NPAD
    unsigned int* adj = (unsigned int*)(cursor + NPAD);    // NPAD*64 fixed slots

    // ---- zero deg+cursor, then deg atomics overlapped with pools-zero + W-pack ----
    k_zero<<<NBLK_N, 256, 0, stream>>>(deg, cursor);
    k_deginit<<<DEG_BLOCKS + INIT_BLOCKS, 256, 0, stream>>>(ei, deg, gsum0, W1, W2, wf);
    k_dis<<<NBLK_N, 256, 0, stream>>>(deg, dis);

    // ---- gemm1 (LDS W, dis-folded A) overlapped with fixed-slot CSR fill ----
    k_fillgemm<<<GEMM_BLOCKS + FILL_BLOCKS, 256, 0, stream>>>(x, wf, dis, hbuf, ei, cursor, adj);

    // ---- conv1 + pool0 + fused gemm2 -> h2' ----
    k_conv<<<NN / 16, 256, 0, stream>>>(hbuf, adj, deg, dis, b1, batch,
                                        wf + 16384, h2b, gsum0, gmax0, cnt, 2 | 4);
    // ---- conv2 + pool1 ----
    k_conv<<<NN / 16, 256, 0, stream>>>(h2b, adj, deg, dis, b2, batch,
                                        (const unsigned short*)nullptr, (unsigned short*)nullptr,
                                        gsum1, gmax1, cnt, 0);

    // ---- MLP head ----
    k_mlp<<<GG, 256, 0, stream>>>(gsum0, gmax0, gsum1, gmax1, cnt, lW1, lb1, lW2, lb2, out);
}

// Round 16
// 182.444 us; speedup vs baseline: 1.0541x; 1.0541x over previous
//
#include <hip/hip_runtime.h>
#include <hip/hip_bf16.h>

#define NN 50000
#define EE 800000
#define DD 128
#define HH 128
#define CC 16
#define GG 512
#define NBLK_SCAN 196    // ceil(50000/256)
#define NPAD 50176       // padded rows for bf16 feature buffers
#define GEMM_BLOCKS 782  // ceil(50000/64)
#define FILL_BLOCKS 3125
#define DEG_BLOCKS 3125
#define INIT_BLOCKS 64
#define POOLF (4 * GG * HH + GG)   // pool floats (gsum0,gmax0,gsum1,gmax1,cnt)

typedef __attribute__((ext_vector_type(8))) short short8v;
typedef __attribute__((ext_vector_type(8))) unsigned short ushort8v;
typedef __attribute__((ext_vector_type(4))) float f32x4;

__device__ inline unsigned short f2bf(float x) {  // RNE
    unsigned int u = __float_as_uint(x);
    u += 0x7fffu + ((u >> 16) & 1u);
    return (unsigned short)(u >> 16);
}

// ---------------- zero deg (must precede deg atomics) ----------------
__global__ __launch_bounds__(256) void k_zero(int* __restrict__ deg) {
    int i = blockIdx.x * 256 + threadIdx.x;
    if (i < NPAD) deg[i] = 0;
}

// ---------------- deg atomics (blocks 0..3124) + pools-zero/W-pack (extra blocks) ----------------
__global__ __launch_bounds__(256) void k_deginit(const int* __restrict__ ei, int* __restrict__ deg,
                                                 float* __restrict__ pools,
                                                 const float* __restrict__ W1, const float* __restrict__ W2,
                                                 unsigned short* __restrict__ Wf) {
    if (blockIdx.x < DEG_BLOCKS) {
        int e = blockIdx.x * 256 + threadIdx.x;
        if (e < EE) atomicAdd(&deg[ei[EE + e]], 1);
    } else {
        int t2 = (blockIdx.x - DEG_BLOCKS) * 256 + threadIdx.x;
        const int nt2 = INIT_BLOCKS * 256;
        for (int i = t2; i < POOLF; i += nt2) pools[i] = 0.0f;
        for (int idx = t2; idx < 4096; idx += nt2) {
            const float* W = (idx >> 11) ? W2 : W1;
            int id2 = idx & 2047;
            int lane = id2 & 63, ct = (id2 >> 6) & 7, kt = id2 >> 9;
            int col = ct * 16 + (lane & 15);
            int k0 = kt * 32 + (lane >> 4) * 8;
            ushort8v v;
            #pragma unroll
            for (int j = 0; j < 8; ++j) v[j] = f2bf(W[(k0 + j) * 128 + col]);
            *(ushort8v*)(Wf + idx * 8) = v;
        }
    }
}

// ---------------- scan level 1 (+ fused dis = rsqrt(deg+1)) ----------------
__global__ __launch_bounds__(256) void k_scan1(const int* __restrict__ deg,
                                               int* __restrict__ offs, int* __restrict__ bsum,
                                               float* __restrict__ dis) {
    __shared__ int tmp[256];
    int i = blockIdx.x * 256 + threadIdx.x;
    int v = (i < NN) ? deg[i] : 0;
    if (i < NN) dis[i] = rsqrtf((float)v + 1.0f);  // +1 self loop
    tmp[threadIdx.x] = v;
    __syncthreads();
    for (int off = 1; off < 256; off <<= 1) {
        int t = (threadIdx.x >= off) ? tmp[threadIdx.x - off] : 0;
        __syncthreads();
        tmp[threadIdx.x] += t;
        __syncthreads();
    }
    if (i < NN) offs[i] = tmp[threadIdx.x] - v;  // exclusive within block
    if (threadIdx.x == 255) bsum[blockIdx.x] = tmp[255];
}

// ---------------- scan levels 2+3 fused ----------------
__global__ __launch_bounds__(256) void k_scan23(int* __restrict__ offs, const int* __restrict__ bsum,
                                                int* __restrict__ cursor) {
    __shared__ int sdata[256];
    int t = threadIdx.x;
    sdata[t] = (t < (int)blockIdx.x && t < NBLK_SCAN) ? bsum[t] : 0;
    __syncthreads();
    for (int off = 128; off > 0; off >>= 1) {
        if (t < off) sdata[t] += sdata[t + off];
        __syncthreads();
    }
    int base = sdata[0];
    int i = blockIdx.x * 256 + t;
    if (i < NN) {
        int v = offs[i] + base;
        offs[i] = v;
        cursor[i] = v;
    }
}

// ---------------- fused launch: gemm1 (blocks 0..781, LDS W, dis folded into A) + CSR fill ----------------
// gemm: O[row] = bf16( (Af[row]*dis[row]) @ W1 )
// fill (r8-exact): adj[pos] = (src<<16) | bf16(dis[s]*dis[d])
//   -- the dis gathers stagger thread arrival at the cursor atomic + scattered store;
//   -- plain stores: L2 write-combines the scattered 4B adj writes (NT store was -20%, r13)
__global__ __launch_bounds__(256) void k_fillgemm(const float* __restrict__ Af,
                                                  const unsigned short* __restrict__ Wf,
                                                  const float* __restrict__ dis,
                                                  unsigned short* __restrict__ O,
                                                  const int* __restrict__ ei,
                                                  int* __restrict__ cursor,
                                                  unsigned int* __restrict__ adj) {
    __shared__ unsigned short Wl[16384];  // 32 KB (gemm branch only)
    if (blockIdx.x < GEMM_BLOCKS) {
        #pragma unroll
        for (int idx = threadIdx.x; idx < 2048; idx += 256)
            *(ushort8v*)(Wl + idx * 8) = *(const ushort8v*)(Wf + idx * 8);
        __syncthreads();

        int wid = threadIdx.x >> 6, lane = threadIdx.x & 63;
        int b = lane >> 4;
        int row = blockIdx.x * 64 + wid * 16 + (lane & 15);
        int r = min(row, NN - 1);
        float dr = dis[r];                    // A row scale (norm factored: h' = (x*dis)@W)
        const float* ap = Af + (size_t)r * 128 + b * 8;
        short8v a[4];
        #pragma unroll
        for (int kt = 0; kt < 4; ++kt) {
            float4 f0 = *(const float4*)(ap + kt * 32);
            float4 f1 = *(const float4*)(ap + kt * 32 + 4);
            short8v v;
            v[0] = (short)f2bf(f0.x * dr); v[1] = (short)f2bf(f0.y * dr);
            v[2] = (short)f2bf(f0.z * dr); v[3] = (short)f2bf(f0.w * dr);
            v[4] = (short)f2bf(f1.x * dr); v[5] = (short)f2bf(f1.y * dr);
            v[6] = (short)f2bf(f1.z * dr); v[7] = (short)f2bf(f1.w * dr);
            a[kt] = v;
        }
        f32x4 z = 0.0f;
        f32x4 acc[8] = {z, z, z, z, z, z, z, z};
        #pragma unroll
        for (int kt = 0; kt < 4; ++kt) {
            #pragma unroll
            for (int ct = 0; ct < 8; ++ct) {
                short8v bfrag = *(const short8v*)(Wl + ((kt * 8 + ct) * 64 + lane) * 8);
                acc[ct] = __builtin_amdgcn_mfma_f32_16x16x32_bf16(a[kt], bfrag, acc[ct], 0, 0, 0);
            }
        }
        // C/D: row = (lane>>4)*4 + j, col = ct*16 + (lane&15)   [m89-verified]
        int orow = blockIdx.x * 64 + wid * 16 + b * 4;
        unsigned short* op = O + (size_t)orow * 128 + (lane & 15);
        #pragma unroll
        for (int j = 0; j < 4; ++j) {
            #pragma unroll
            for (int ct = 0; ct < 8; ++ct)
                op[(size_t)j * 128 + ct * 16] = f2bf(acc[ct][j]);
        }
    } else {
        int e = (blockIdx.x - GEMM_BLOCKS) * 256 + threadIdx.x;
        if (e < EE) {
            int s = ei[e];
            int d = ei[EE + e];
            float nrm = dis[s] * dis[d];
            int pos = atomicAdd(&cursor[d], 1);
            adj[pos] = ((unsigned int)s << 16) | (unsigned int)f2bf(nrm);
        }
    }
}

// ---------------- fused gather conv + self + bias + relu + pool (+ optional fused GEMM2) ----------------
// h holds h' = (x*dis)@W ; conv computes relu(dis[d] * (sum_{s in N(d)} h'[s] + h'[d]) + bias)
// adj entry = (src<<16)|norm16 ; only src (e>>16) is used.
// flags: 2 = count nodes per graph, 4 = fused gemm2 epilogue ((lacc*dis) @ W2f -> h2out)
__global__ __launch_bounds__(256) void k_conv(const unsigned short* __restrict__ h,
                                              const unsigned int* __restrict__ adj,
                                              const int* __restrict__ row_start,
                                              const int* __restrict__ deg,
                                              const float* __restrict__ dis,
                                              const float* __restrict__ bias,
                                              const int* __restrict__ batch,
                                              const unsigned short* __restrict__ W2f,
                                              unsigned short* __restrict__ h2out,
                                              float* __restrict__ gsum,
                                              float* __restrict__ gmax,
                                              float* __restrict__ cnt,
                                              int flags) {
    __shared__ float lacc[16][132];   // stride 132 -> 16B-aligned rows, 2-way bank alias only
    __shared__ int lb[16];
    __shared__ float sdis[16];
    const int tid = threadIdx.x;
    const int wid = tid >> 6, lane = tid & 63;
    const int g = lane >> 4, l = lane & 15;
    const int nrow = wid * 4 + g;
    const int node = blockIdx.x * 16 + nrow;
    const int fb = l * 8;   // 8 features per lane

    const float di = dis[node];
    const uint4 hv = *(const uint4*)(h + (size_t)node * 128 + fb);
    const float4 bv0 = *(const float4*)(bias + fb);
    const float4 bv1 = *(const float4*)(bias + fb + 4);
    float acc[8];
    acc[0] = __uint_as_float(hv.x << 16);
    acc[1] = __uint_as_float(hv.x & 0xffff0000u);
    acc[2] = __uint_as_float(hv.y << 16);
    acc[3] = __uint_as_float(hv.y & 0xffff0000u);
    acc[4] = __uint_as_float(hv.z << 16);
    acc[5] = __uint_as_float(hv.z & 0xffff0000u);
    acc[6] = __uint_as_float(hv.w << 16);
    acc[7] = __uint_as_float(hv.w & 0xffff0000u);

    const int rs = row_start[node];
    const int n  = deg[node];           // uniform within 16-lane group
    const unsigned int* ap = adj + rs;
    const int sl = lane & 48;           // group base lane (g*16)
    const int nfull = n & ~15;

    for (int k = 0; k < nfull; k += 16) {
        unsigned int e = ap[k + l];     // cooperative adj load
        #pragma unroll
        for (int j = 0; j < 16; ++j) {
            unsigned int ej = __shfl(e, sl + j) >> 16;   // src only
            const uint4 v = *(const uint4*)(h + (size_t)ej * 128 + fb);
            acc[0] += __uint_as_float(v.x << 16);
            acc[1] += __uint_as_float(v.x & 0xffff0000u);
            acc[2] += __uint_as_float(v.y << 16);
            acc[3] += __uint_as_float(v.y & 0xffff0000u);
            acc[4] += __uint_as_float(v.z << 16);
            acc[5] += __uint_as_float(v.z & 0xffff0000u);
            acc[6] += __uint_as_float(v.w << 16);
            acc[7] += __uint_as_float(v.w & 0xffff0000u);
        }
    }
    if (nfull < n) {  // masked tail window
        unsigned int e = ap[min(nfull + l, n - 1)];
        #pragma unroll
        for (int j = 0; j < 16; ++j) {
            unsigned int ej = __shfl(e, sl + j) >> 16;
            float w = (nfull + j < n) ? 1.0f : 0.0f;
            const uint4 v = *(const uint4*)(h + (size_t)ej * 128 + fb);
            acc[0] = fmaf(__uint_as_float(v.x << 16),         w, acc[0]);
            acc[1] = fmaf(__uint_as_float(v.x & 0xffff0000u), w, acc[1]);
            acc[2] = fmaf(__uint_as_float(v.y << 16),         w, acc[2]);
            acc[3] = fmaf(__uint_as_float(v.y & 0xffff0000u), w, acc[3]);
            acc[4] = fmaf(__uint_as_float(v.z << 16),         w, acc[4]);
            acc[5] = fmaf(__uint_as_float(v.z & 0xffff0000u), w, acc[5]);
            acc[6] = fmaf(__uint_as_float(v.w << 16),         w, acc[6]);
            acc[7] = fmaf(__uint_as_float(v.w & 0xffff0000u), w, acc[7]);
        }
    }
    float bvv[8] = {bv0.x, bv0.y, bv0.z, bv0.w, bv1.x, bv1.y, bv1.z, bv1.w};
    #pragma unroll
    for (int p = 0; p < 8; ++p) {
        float v = fmaxf(fmaf(di, acc[p], bvv[p]), 0.0f);
        lacc[nrow][fb + p] = v;
    }
    if (l == 0) lb[nrow] = batch[node];
    if (tid < 16) sdis[tid] = dis[blockIdx.x * 16 + tid];
    __syncthreads();

    // ---- block pool pre-reduction over 16 sorted nodes ----
    {
        const int f = tid & 127;
        const bool domax = tid >= 128;
        float s = lacc[0][f];
        int cur = lb[0], run = 1;
        #pragma unroll
        for (int w = 1; w < 16; ++w) {
            float a = lacc[w][f];
            if (lb[w] == cur) {
                s = domax ? fmaxf(s, a) : (s + a);
                ++run;
            } else {
                if (domax) {
                    atomicMax((int*)&gmax[cur * 128 + f], __float_as_int(s));
                } else {
                    atomicAdd(&gsum[cur * 128 + f], s);
                    if (f == 0 && (flags & 2)) atomicAdd(cnt + cur, (float)run);
                }
                s = a; cur = lb[w]; run = 1;
            }
        }
        if (domax) {
            atomicMax((int*)&gmax[cur * 128 + f], __float_as_int(s));
        } else {
            atomicAdd(&gsum[cur * 128 + f], s);
            if (f == 0 && (flags & 2)) atomicAdd(cnt + cur, (float)run);
        }
    }

    // ---- fused GEMM2: h2' = (lacc*dis) @ W2, written to h2out (dis folded into A rows) ----
    if (flags & 4) {
        const int ct0 = wid * 2, ct1 = wid * 2 + 1;
        const float dr = sdis[lane & 15];   // A row = lane&15
        f32x4 c0 = 0.0f, c1 = 0.0f;
        #pragma unroll
        for (int kt = 0; kt < 4; ++kt) {
            const float* arow = &lacc[lane & 15][kt * 32 + (lane >> 4) * 8];
            float4 fa = *(const float4*)arow;
            float4 fc = *(const float4*)(arow + 4);
            short8v af;
            af[0] = (short)f2bf(fa.x * dr); af[1] = (short)f2bf(fa.y * dr);
            af[2] = (short)f2bf(fa.z * dr); af[3] = (short)f2bf(fa.w * dr);
            af[4] = (short)f2bf(fc.x * dr); af[5] = (short)f2bf(fc.y * dr);
            af[6] = (short)f2bf(fc.z * dr); af[7] = (short)f2bf(fc.w * dr);
            short8v b0 = *(const short8v*)(W2f + ((kt * 8 + ct0) * 64 + lane) * 8);
            short8v b1 = *(const short8v*)(W2f + ((kt * 8 + ct1) * 64 + lane) * 8);
            c0 = __builtin_amdgcn_mfma_f32_16x16x32_bf16(af, b0, c0, 0, 0, 0);
            c1 = __builtin_amdgcn_mfma_f32_16x16x32_bf16(af, b1, c1, 0, 0, 0);
        }
        const int node0 = blockIdx.x * 16;
        #pragma unroll
        for (int j = 0; j < 4; ++j) {
            int r = (lane >> 4) * 4 + j;
            unsigned short* op = h2out + (size_t)(node0 + r) * 128 + (lane & 15);
            op[ct0 * 16] = f2bf(c0[j]);
            op[ct1 * 16] = f2bf(c1[j]);
        }
    }
}

// ---------------- final MLP: one block per graph ----------------
__global__ __launch_bounds__(256) void k_mlp(const float* __restrict__ gsum0,
                                             const float* __restrict__ gmax0,
                                             const float* __restrict__ gsum1,
                                             const float* __restrict__ gmax1,
                                             const float* __restrict__ cnt,
                                             const float* __restrict__ lW1,
                                             const float* __restrict__ lb1,
                                             const float* __restrict__ lW2,
                                             const float* __restrict__ lb2,
                                             float* __restrict__ out) {
    __shared__ float gl[512];
    __shared__ float hb[256];
    __shared__ float part[256];
    int r = blockIdx.x;
    float inv = 1.0f / fmaxf(cnt[r], 1.0f);
    for (int k = threadIdx.x; k < 512; k += 256) {
        int seg = k >> 7, f = k & 127;
        float v;
        if (seg == 0)      v = gsum0[r * 128 + f] * inv;
        else if (seg == 1) v = gmax0[r * 128 + f];
        else if (seg == 2) v = gsum1[r * 128 + f] * inv;
        else               v = gmax1[r * 128 + f];
        gl[k] = v;
    }
    __syncthreads();
    {
        int j = threadIdx.x;
        float acc = lb1[j];
        for (int k = 0; k < 512; ++k) acc += gl[k] * lW1[k * 256 + j];
        hb[j] = fmaxf(acc, 0.f);
    }
    __syncthreads();
    {
        int c = threadIdx.x & 15, ch = threadIdx.x >> 4;
        float p = 0.f;
        #pragma unroll
        for (int j2 = 0; j2 < 16; ++j2) p += hb[ch * 16 + j2] * lW2[(ch * 16 + j2) * 16 + c];
        part[threadIdx.x] = p;
    }
    __syncthreads();
    if (threadIdx.x < 16) {
        float s = lb2[threadIdx.x];
        #pragma unroll
        for (int ch2 = 0; ch2 < 16; ++ch2) s += part[ch2 * 16 + threadIdx.x];
        out[r * 16 + threadIdx.x] = s;
    }
}

extern "C" void kernel_launch(void* const* d_in, const int* in_sizes, int n_in,
                              void* d_out, int out_size, void* d_ws, size_t ws_size,
                              hipStream_t stream) {
    const float* x    = (const float*)d_in[0];
    const int*   ei   = (const int*)d_in[1];
    const int*   batch= (const int*)d_in[2];
    const float* W1   = (const float*)d_in[3];
    const float* b1   = (const float*)d_in[4];
    const float* W2   = (const float*)d_in[5];
    const float* b2   = (const float*)d_in[6];
    const float* lW1  = (const float*)d_in[7];
    const float* lb1  = (const float*)d_in[8];
    const float* lW2  = (const float*)d_in[9];
    const float* lb2  = (const float*)d_in[10];
    float* out = (float*)d_out;

    // ---- workspace layout ----
    unsigned short* hbuf = (unsigned short*)d_ws;          // NPAD*128 bf16 (h1')
    unsigned short* h2b  = hbuf + (size_t)NPAD * 128;      // NPAD*128 bf16 (h2')
    unsigned short* wf   = h2b + (size_t)NPAD * 128;       // 2*16384 bf16 frag-packed W1,W2
    float* dis   = (float*)(wf + 32768);                   // NPAD f32
    float* gsum0 = dis + NPAD;
    float* gmax0 = gsum0 + GG * HH;
    float* gsum1 = gmax0 + GG * HH;
    float* gmax1 = gsum1 + GG * HH;
    float* cnt   = gmax1 + GG * HH;                        // G
    int*   deg    = (int*)(cnt + GG);                      // NPAD
    int*   offs   = deg + NPAD;
    int*   cursor = offs + NPAD;
    int*   bsum   = cursor + NPAD;                         // 256
    unsigned int* adj = (unsigned int*)(bsum + 256);       // E uint (src<<16|norm) + pad

    // ---- zero deg, then deg atomics overlapped with pools-zero + W-pack ----
    k_zero<<<NBLK_SCAN, 256, 0, stream>>>(deg);
    k_deginit<<<DEG_BLOCKS + INIT_BLOCKS, 256, 0, stream>>>(ei, deg, gsum0, W1, W2, wf);

    // ---- scan ----
    k_scan1<<<NBLK_SCAN, 256, 0, stream>>>(deg, offs, bsum, dis);
    k_scan23<<<NBLK_SCAN, 256, 0, stream>>>(offs, bsum, cursor);

    // ---- gemm1 (LDS W, dis-folded A) overlapped with CSR fill (r8-exact fill, no NT) ----
    k_fillgemm<<<GEMM_BLOCKS + FILL_BLOCKS, 256, 0, stream>>>(x, wf, dis, hbuf, ei, cursor, adj);

    // ---- conv1 + pool0 + fused gemm2 -> h2' ----
    k_conv<<<NN / 16, 256, 0, stream>>>(hbuf, adj, offs, deg, dis, b1, batch,
                                        wf + 16384, h2b, gsum0, gmax0, cnt, 2 | 4);
    // ---- conv2 + pool1 ----
    k_conv<<<NN / 16, 256, 0, stream>>>(h2b, adj, offs, deg, dis, b2, batch,
                                        (const unsigned short*)nullptr, (unsigned short*)nullptr,
                                        gsum1, gmax1, cnt, 0);

    // ---- MLP head ----
    k_mlp<<<GG, 256, 0, stream>>>(gsum0, gmax0, gsum1, gmax1, cnt, lW1, lb1, lW2, lb2, out);
}